// Round 1
// baseline (254.047 us; speedup 1.0000x reference)
//
#include <hip/hip_runtime.h>
#include <math.h>

#define Bsz 4096
#define Ssz 200
#define Dsz 64
#define NK  5
#define NTHREADS 512

__global__ void zero_loss_kernel(float* loss) {
    if (threadIdx.x == 0) *loss = 0.0f;
}

__global__ __launch_bounds__(NTHREADS) void tan_kernel(
    const int* __restrict__ x, const float* __restrict__ y,
    const float* __restrict__ emb_table,
    const float* __restrict__ att_w, const float* __restrict__ att_b,
    const float* __restrict__ W0, const float* __restrict__ W1,
    const float* __restrict__ W2, const float* __restrict__ W3,
    const float* __restrict__ W4,
    float* __restrict__ out_logit, float* __restrict__ loss_out)
{
    __shared__ float emb[Ssz][Dsz];     // 51200 B
    __shared__ int   xs[Ssz];           //   800 B
    __shared__ float att[NK][Ssz];      //  4000 B  (logits, then scores in-place)
    __shared__ float urp[2][NK][Dsz];   //  2560 B
    __shared__ float ur[NK][Dsz];       //  1280 B
    __shared__ float wu[18];            //    72 B
    // total ~59.9 KB -> 2 blocks/CU -> 16 waves/CU

    const int b   = blockIdx.x;
    const int tid = threadIdx.x;
    const int w   = tid >> 6;   // wave id (0..7)
    const int l   = tid & 63;   // lane
    const int c   = tid & 15;   // float4-column within a row (invariant: 512%16==0)

    // ---- stage indices ----
    for (int s = tid; s < Ssz; s += NTHREADS) xs[s] = x[(size_t)b * Ssz + s];

    // preload att_w fragment (4 d's per 16-lane group) + att_b into registers
    float4 aw[NK];
    float  ab[NK];
#pragma unroll
    for (int k = 0; k < NK; ++k) {
        aw[k] = *(const float4*)(att_w + k * Dsz + c * 4);
        ab[k] = att_b[k];
    }
    __syncthreads();

    // ---- gather embed rows + fused attention-logit dot ----
    // 16 lanes cooperate per row; wave's b128 LDS write spans 1024 contiguous B.
    for (int i = tid; i < Ssz * 16; i += NTHREADS) {
        int s = i >> 4;
        float4 v = *(const float4*)(emb_table + (size_t)xs[s] * Dsz + c * 4);
        *(float4*)(&emb[s][c * 4]) = v;
        float p[NK];
#pragma unroll
        for (int k = 0; k < NK; ++k)
            p[k] = v.x * aw[k].x + v.y * aw[k].y + v.z * aw[k].z + v.w * aw[k].w;
#pragma unroll
        for (int m = 1; m <= 8; m <<= 1) {
#pragma unroll
            for (int k = 0; k < NK; ++k) p[k] += __shfl_xor(p[k], m);
        }
        if (c == 0) {
#pragma unroll
            for (int k = 0; k < NK; ++k) att[k][s] = tanhf(p[k] + ab[k]);
        }
    }
    __syncthreads();

    // ---- softmax over s for each k (wave w handles k=w, w<5) ----
    if (w < NK) {
        const int k = w;
        float vals[4];
        float mx = -1e30f;
#pragma unroll
        for (int j = 0; j < 4; ++j) {
            int s = l + 64 * j;
            vals[j] = (s < Ssz) ? att[k][s] : -1e30f;
            mx = fmaxf(mx, vals[j]);
        }
#pragma unroll
        for (int m = 32; m >= 1; m >>= 1) mx = fmaxf(mx, __shfl_xor(mx, m));
        float sum = 0.f;
#pragma unroll
        for (int j = 0; j < 4; ++j) {
            vals[j] = __expf(vals[j] - mx);   // OOB lanes: exp(-huge) -> 0
            sum += vals[j];
        }
#pragma unroll
        for (int m = 32; m >= 1; m >>= 1) sum += __shfl_xor(sum, m);
        float inv = 1.0f / sum;
#pragma unroll
        for (int j = 0; j < 4; ++j) {
            int s = l + 64 * j;
            if (s < Ssz) att[k][s] = vals[j] * inv;
        }
    }
    __syncthreads();

    // ---- user_rep[k][d] = sum_s emb[s][d] * score[k][s] ----
    // 10 tasks (k, s-half) over 8 waves; lane = d.
    for (int t = w; t < 2 * NK; t += 8) {
        int k = t >> 1, h = t & 1;
        float acc = 0.f;
        int s0 = h * 100;
        for (int s = s0; s < s0 + 100; ++s)
            acc += emb[s][l] * att[k][s];   // consecutive + broadcast: conflict-free
        urp[h][k][l] = acc;
    }
    __syncthreads();
    for (int i = tid; i < NK * Dsz; i += NTHREADS) {
        int k = i >> 6, d = i & 63;
        ur[k][d] = urp[0][k][d] + urp[1][k][d];
    }
    __syncthreads();

    // ---- W_user[j] = ur[g(j)] . W_g[r(j)]  (18 dots of 64) ----
    for (int j = w; j < 18; j += 8) {
        const float* Wp; int g, c0;
        if      (j < 2)  { g = 0; c0 = 0;  Wp = W0; }
        else if (j < 6)  { g = 1; c0 = 2;  Wp = W1; }
        else if (j < 10) { g = 2; c0 = 6;  Wp = W2; }
        else if (j < 12) { g = 3; c0 = 10; Wp = W3; }
        else             { g = 4; c0 = 12; Wp = W4; }
        float p = ur[g][l] * Wp[(j - c0) * Dsz + l];
#pragma unroll
        for (int m = 32; m >= 1; m >>= 1) p += __shfl_xor(p, m);
        if (l == 0) wu[j] = p;
    }
    __syncthreads();

    // ---- per-group softmax -> logits; cross-entropy -> loss ----
    if (tid == 0) {
        const int LEN[5] = {2, 4, 4, 2, 6};
        float lossb = 0.f;
        float* op = out_logit + (size_t)b * 18;
        const float* yp = y + (size_t)b * 18;
        int c0 = 0;
#pragma unroll
        for (int g = 0; g < 5; ++g) {
            float mx = -1e30f;
            for (int j = 0; j < LEN[g]; ++j) mx = fmaxf(mx, wu[c0 + j]);
            float sum = 0.f;
            for (int j = 0; j < LEN[g]; ++j) sum += __expf(wu[c0 + j] - mx);
            float inv = 1.0f / sum;
            float lse = mx + __logf(sum);
            for (int j = 0; j < LEN[g]; ++j) {
                op[c0 + j] = __expf(wu[c0 + j] - mx) * inv;
                lossb += (lse - wu[c0 + j]) * yp[c0 + j];
            }
            c0 += LEN[g];
        }
        atomicAdd(loss_out, lossb * (1.0f / Bsz));
    }
}

extern "C" void kernel_launch(void* const* d_in, const int* in_sizes, int n_in,
                              void* d_out, int out_size, void* d_ws, size_t ws_size,
                              hipStream_t stream) {
    const int*   x   = (const int*)d_in[0];
    const float* y   = (const float*)d_in[1];
    const float* emb = (const float*)d_in[2];
    const float* aw  = (const float*)d_in[3];
    const float* ab  = (const float*)d_in[4];
    const float* W0  = (const float*)d_in[5];
    const float* W1  = (const float*)d_in[6];
    const float* W2  = (const float*)d_in[7];
    const float* W3  = (const float*)d_in[8];
    const float* W4  = (const float*)d_in[9];
    float* out  = (float*)d_out;
    float* loss = out + (size_t)Bsz * 18;   // tuple layout: logits flat, then scalar loss

    zero_loss_kernel<<<1, 64, 0, stream>>>(loss);
    tan_kernel<<<Bsz, NTHREADS, 0, stream>>>(x, y, emb, aw, ab,
                                             W0, W1, W2, W3, W4, out, loss);
}

// Round 2
// 210.016 us; speedup vs baseline: 1.2097x; 1.2097x over previous
//
#include <hip/hip_runtime.h>
#include <math.h>

#define Bsz 4096
#define Ssz 200
#define Dsz 64
#define NK  5
#define NT  512
#define PADQ 17   // float4 stride per emb row (68 floats) -> bank-balanced

__global__ void zero_loss_kernel(float* loss) {
    if (threadIdx.x == 0) *loss = 0.0f;
}

#define FMA4(A, V, S) do { (A).x += (V).x*(S); (A).y += (V).y*(S); \
                           (A).z += (V).z*(S); (A).w += (V).w*(S); } while (0)

__global__ __launch_bounds__(NT, 4) void tan_kernel(
    const int* __restrict__ x, const float* __restrict__ y,
    const float* __restrict__ emb_table,
    const float* __restrict__ att_w, const float* __restrict__ att_b,
    const float* __restrict__ W0, const float* __restrict__ W1,
    const float* __restrict__ W2, const float* __restrict__ W3,
    const float* __restrict__ W4,
    float* __restrict__ out_logit, float* __restrict__ loss_out)
{
    __shared__ float4 embq[Ssz * PADQ];   // 54400 B; later overlaid by urp[8][5][16] float4
    __shared__ float  att[NK][Ssz];       //  4000 B (logits, then scores in-place)
    __shared__ float  ur[NK][Dsz];        //  1280 B
    __shared__ float  wu[18];
    // total ~59.8 KB -> 2 blocks/CU -> 16 waves/CU

    const int b   = blockIdx.x;
    const int tid = threadIdx.x;
    const int w   = tid >> 6;
    const int l   = tid & 63;

    // ---- phase 1: gather (2 lanes/row, 8x b128 each) + fused attention dot ----
    if (tid < 2 * Ssz) {
        const int s = tid >> 1;
        const int h = tid & 1;
        const int xi = x[b * Ssz + s];
        const float4* row = (const float4*)(emb_table + (size_t)xi * Dsz) + h * 8;
        const float4* awp = (const float4*)att_w;   // [5][16] float4
        float4 v[8];
#pragma unroll
        for (int j = 0; j < 8; ++j) v[j] = row[j];
        float p[NK] = {0.f, 0.f, 0.f, 0.f, 0.f};
#pragma unroll
        for (int j = 0; j < 8; ++j) {
#pragma unroll
            for (int k = 0; k < NK; ++k) {
                float4 a = awp[k * 16 + h * 8 + j];
                p[k] += v[j].x*a.x + v[j].y*a.y + v[j].z*a.z + v[j].w*a.w;
            }
        }
#pragma unroll
        for (int j = 0; j < 8; ++j) embq[s * PADQ + h * 8 + j] = v[j];
#pragma unroll
        for (int k = 0; k < NK; ++k) p[k] += __shfl_xor(p[k], 1);
        if (h == 0) {
#pragma unroll
            for (int k = 0; k < NK; ++k) att[k][s] = tanhf(p[k] + att_b[k]);
        }
    }
    __syncthreads();

    // ---- softmax over s for each k (wave w handles k=w, w<5) ----
    if (w < NK) {
        const int k = w;
        float vals[4];
        float mx = -1e30f;
#pragma unroll
        for (int j = 0; j < 4; ++j) {
            int s = l + 64 * j;
            vals[j] = (s < Ssz) ? att[k][s] : -1e30f;
            mx = fmaxf(mx, vals[j]);
        }
#pragma unroll
        for (int m = 32; m >= 1; m >>= 1) mx = fmaxf(mx, __shfl_xor(mx, m));
        float sum = 0.f;
#pragma unroll
        for (int j = 0; j < 4; ++j) {
            vals[j] = __expf(vals[j] - mx);
            sum += vals[j];
        }
#pragma unroll
        for (int m = 32; m >= 1; m >>= 1) sum += __shfl_xor(sum, m);
        float inv = 1.0f / sum;
#pragma unroll
        for (int j = 0; j < 4; ++j) {
            int s = l + 64 * j;
            if (s < Ssz) att[k][s] = vals[j] * inv;
        }
    }
    __syncthreads();

    // ---- phase 2: user_rep, 128 threads, thread (c,j) owns d-frag c, quads j+8m ----
    float4 acc[NK];
    const int c2 = tid & 15;
    const int j2 = tid >> 4;
    if (tid < 128) {
#pragma unroll
        for (int k = 0; k < NK; ++k) acc[k] = float4{0.f, 0.f, 0.f, 0.f};
        for (int q = j2; q < 50; q += 8) {
            float4 sc[NK];
#pragma unroll
            for (int k = 0; k < NK; ++k) sc[k] = ((const float4*)att[k])[q];
            float4 v0 = embq[(4*q + 0) * PADQ + c2];
            float4 v1 = embq[(4*q + 1) * PADQ + c2];
            float4 v2 = embq[(4*q + 2) * PADQ + c2];
            float4 v3 = embq[(4*q + 3) * PADQ + c2];
#pragma unroll
            for (int k = 0; k < NK; ++k) {
                FMA4(acc[k], v0, sc[k].x);
                FMA4(acc[k], v1, sc[k].y);
                FMA4(acc[k], v2, sc[k].z);
                FMA4(acc[k], v3, sc[k].w);
            }
        }
    }
    __syncthreads();   // all embq reads complete -> safe to overlay

    if (tid < 128) {
        float4* urp = embq;   // overlay: urp[(j*NK + k)*16 + c]
#pragma unroll
        for (int k = 0; k < NK; ++k) urp[(j2 * NK + k) * 16 + c2] = acc[k];
    }
    __syncthreads();

    if (tid < NK * Dsz) {
        const int k = tid >> 6, d = tid & 63;
        const float* urpf = (const float*)embq;
        float sum = 0.f;
#pragma unroll
        for (int j = 0; j < 8; ++j) sum += urpf[(j * NK + k) * 64 + d];
        ur[k][d] = sum;
    }
    __syncthreads();

    // ---- W_user[j] = ur[g(j)] . W_g[r(j)]  (18 dots of 64) ----
    for (int j = w; j < 18; j += 8) {
        const float* Wp; int g, c0;
        if      (j < 2)  { g = 0; c0 = 0;  Wp = W0; }
        else if (j < 6)  { g = 1; c0 = 2;  Wp = W1; }
        else if (j < 10) { g = 2; c0 = 6;  Wp = W2; }
        else if (j < 12) { g = 3; c0 = 10; Wp = W3; }
        else             { g = 4; c0 = 12; Wp = W4; }
        float p = ur[g][l] * Wp[(j - c0) * Dsz + l];
#pragma unroll
        for (int m = 32; m >= 1; m >>= 1) p += __shfl_xor(p, m);
        if (l == 0) wu[j] = p;
    }
    __syncthreads();

    // ---- per-group softmax -> logits; cross-entropy -> loss (5 lanes of wave 0) ----
    if (w == 0) {
        float lossb = 0.f;
        if (l < NK) {
            const int LEN[5] = {2, 4, 4, 2, 6};
            const int C0[5]  = {0, 2, 6, 10, 12};
            const int g = l, c0 = C0[g], len = LEN[g];
            float* op = out_logit + (size_t)b * 18;
            const float* yp = y + (size_t)b * 18;
            float mx = -1e30f;
            for (int j = 0; j < len; ++j) mx = fmaxf(mx, wu[c0 + j]);
            float sum = 0.f;
            for (int j = 0; j < len; ++j) sum += __expf(wu[c0 + j] - mx);
            float inv = 1.0f / sum;
            float lse = mx + __logf(sum);
            for (int j = 0; j < len; ++j) {
                op[c0 + j] = __expf(wu[c0 + j] - mx) * inv;
                lossb += (lse - wu[c0 + j]) * yp[c0 + j];
            }
        }
#pragma unroll
        for (int m = 1; m <= 4; m <<= 1) lossb += __shfl_xor(lossb, m);
        if (l == 0) atomicAdd(loss_out, lossb * (1.0f / Bsz));
    }
}

extern "C" void kernel_launch(void* const* d_in, const int* in_sizes, int n_in,
                              void* d_out, int out_size, void* d_ws, size_t ws_size,
                              hipStream_t stream) {
    const int*   x   = (const int*)d_in[0];
    const float* y   = (const float*)d_in[1];
    const float* emb = (const float*)d_in[2];
    const float* aw  = (const float*)d_in[3];
    const float* ab  = (const float*)d_in[4];
    const float* W0  = (const float*)d_in[5];
    const float* W1  = (const float*)d_in[6];
    const float* W2  = (const float*)d_in[7];
    const float* W3  = (const float*)d_in[8];
    const float* W4  = (const float*)d_in[9];
    float* out  = (float*)d_out;
    float* loss = out + (size_t)Bsz * 18;

    zero_loss_kernel<<<1, 64, 0, stream>>>(loss);
    tan_kernel<<<Bsz, NT, 0, stream>>>(x, y, emb, aw, ab,
                                       W0, W1, W2, W3, W4, out, loss);
}